// Round 23
// baseline (5644.030 us; speedup 1.0000x reference)
//
#include <hip/hip_runtime.h>
#include <hip/hip_bf16.h>

// Problem constants
#define BB   128
#define SS   512
#define IND  512
#define HID  1024
#define NBLK 256     // 4 row-quarters (mi) x 64 column-groups (jg)
#define GRPBLK 64    // blocks per mi-group (independent sub-GRU)
#define NSTRIPE 8    // stripes per group (one 64B LLC line each)

#define WHH_LD (HID + 8)   // LDS row pad
#define WIH_LD (IND + 8)

typedef __attribute__((ext_vector_type(8))) short s8v;   // 8 x bf16
typedef __attribute__((ext_vector_type(4))) float f4v;   // MFMA accumulator
typedef unsigned long long u64;
typedef unsigned int u32;

__device__ __forceinline__ short f2bf(float f) {
    union { float f; u32 u; } v; v.f = f;
    u32 u = v.u + 0x7FFFu + ((v.u >> 16) & 1u);          // RNE
    return (short)(u >> 16);
}

// h ping-pong layout (bf16): as R8 (PROVEN).
//   bufA (ws): [wg=8][kk=32][kg=4][row 16][8 shorts]
//   bufB (out tail): group mi slice at mi*131072 + (wg&1)*32768 + rest
//
// R22 = R20 (best, 3513us) + ONLY the gh chunk-0 hoist (bisect of R21):
//   gh's first 16 atomic loads issue at the TOP of the step, so their
//   ~0.8us LLC round-trip flies under gi's ~1.5us of work. One fence;
//   gi left untouched (R21's 4 extra gi fences = the regression suspect).
//   Addresses, consumption order, and all MFMA ops unchanged ->
//   bit-identical output. Spill tripwire: WRITE_SIZE must stay ~528MB.

__global__ void __launch_bounds__(128, 1)
gru_persistent(const float* __restrict__ X,     // [B,S,IND]
               const float* __restrict__ Wih,   // [3H, IND]
               const float* __restrict__ Whh,   // [3H, HID]
               const float* __restrict__ bih,   // [3H]
               const float* __restrict__ bhh,   // [3H]
               float* __restrict__ out,         // [B,S,H] ++ [B,H]
               short* __restrict__ bufA,        // ws scratch (even t)
               short* __restrict__ bufB,        // d_out tail region (odd t)
               u64*   __restrict__ ctr)         // 4 groups x 8 stripes, 64B apart
{
    __shared__ __align__(16) short whh_lds[48 * WHH_LD];   // 99072 B
    __shared__ __align__(16) short wih_lds[48 * WIH_LD];   // 49920 B
    __shared__ __align__(16) short xpre[4 * 128 * 8];      //  8192 B [chunk][tid][8]

    const int tid  = threadIdx.x;
    const int wave = tid >> 6;      // 0..1
    const int lane = tid & 63;
    const int blk  = blockIdx.x;
    const int mi   = blk >> 6;      // 0..3 row quarter == barrier group
    const int jg   = blk & 63;      // column group

    // ---- stage weight slices to LDS as bf16 (once; R16/R8 layout) ----
    for (int idx = tid; idx < 48 * (HID / 4); idx += 128) {
        int s = idx / (HID / 4), k4 = idx % (HID / 4);
        int grow = (s >> 4) * HID + jg * 16 + (s & 15);
        float4 v = *(const float4*)(Whh + (size_t)grow * HID + k4 * 4);
        short* d = &whh_lds[s * WHH_LD + k4 * 4];
        d[0] = f2bf(v.x); d[1] = f2bf(v.y); d[2] = f2bf(v.z); d[3] = f2bf(v.w);
    }
    for (int idx = tid; idx < 48 * (IND / 4); idx += 128) {
        int s = idx / (IND / 4), k4 = idx % (IND / 4);
        int grow = (s >> 4) * HID + jg * 16 + (s & 15);
        float4 v = *(const float4*)(Wih + (size_t)grow * IND + k4 * 4);
        short* d = &wih_lds[s * WIH_LD + k4 * 4];
        d[0] = f2bf(v.x); d[1] = f2bf(v.y); d[2] = f2bf(v.z); d[3] = f2bf(v.w);
    }

    const int n  = lane & 15;
    const int kg = lane >> 4;
    const int j  = jg * 16 + n;
    const float bir = bih[j], biz = bih[HID + j], bin_ = bih[2 * HID + j];
    const float bhr = bhh[j], bhz = bhh[HID + j], bhn  = bhh[2 * HID + j];

    const int rowbase = mi * 32 + wave * 16;
    const int wg      = mi * 2 + wave;          // row-group = rowbase/16

    // writer byte offsets (lanes n%4==0 store packed u64 = cols j..j+3)
    const int wkk = j >> 5, wkg = (j >> 3) & 3;
    const u32 rest   = (u32)wkk * 1024u + (u32)wkg * 256u
                     + (u32)kg * 64u + ((u32)(n & 7) << 1);
    const u32 wbyteA = (u32)wg * 32768u + rest;
    const u32 wbyteB = (u32)mi * 131072u + (u32)(wg & 1) * 32768u + rest;

    // reader u64 offsets (lane-contiguous 16B per lane)
    const u64* hbA = (const u64*)bufA + (size_t)wg * 4096 + lane * 2;
    const u64* hbB = (const u64*)bufB + (size_t)mi * 16384
                   + (size_t)(wg & 1) * 4096 + lane * 2;

    const float* xlane = X + (size_t)(rowbase + n) * SS * IND + kg * 8;

    float hkeep[4] = {0.f, 0.f, 0.f, 0.f};      // this lane's own h elements

    // ---- prologue: fill xpre for t=0 (per-thread slices, no sync needed) ----
    {
        const float* xrow = xlane;
        #pragma unroll
        for (int c = 0; c < 4; ++c) {
            float4 a0 = *(const float4*)(xrow + c * 32);
            float4 a1 = *(const float4*)(xrow + c * 32 + 4);
            s8v xv8;
            xv8[0]=f2bf(a0.x); xv8[1]=f2bf(a0.y); xv8[2]=f2bf(a0.z); xv8[3]=f2bf(a0.w);
            xv8[4]=f2bf(a1.x); xv8[5]=f2bf(a1.y); xv8[6]=f2bf(a1.z); xv8[7]=f2bf(a1.w);
            *(s8v*)&xpre[(c * 128 + tid) * 8] = xv8;
        }
    }

    __syncthreads();

    for (int t = 0; t < SS; ++t) {
        f4v acc_r  = {0.f,0.f,0.f,0.f};
        f4v acc_z  = {0.f,0.f,0.f,0.f};
        f4v acc_in = {0.f,0.f,0.f,0.f};
        f4v acc_hn = {0.f,0.f,0.f,0.f};
        s8v areg[32];

        const u64* hb = (t & 1) ? hbA : hbB;                  // h_{t-1}

        // ---- gh chunk-0 loads hoisted to step top: RT hides under gi ----
        if (t > 0) {
            #pragma unroll
            for (int q = 0; q < 8; ++q) {
                u64 lo = __hip_atomic_load(hb + q * 128,
                                           __ATOMIC_RELAXED, __HIP_MEMORY_SCOPE_AGENT);
                u64 hi = __hip_atomic_load(hb + q * 128 + 1,
                                           __ATOMIC_RELAXED, __HIP_MEMORY_SCOPE_AGENT);
                union { u64 qq[2]; s8v v; } u; u.qq[0] = lo; u.qq[1] = hi;
                areg[q] = u.v;
            }
        }
        __builtin_amdgcn_sched_barrier(0);

        // ---- gi: X[:,t,:] @ Wih_slice^T (K=512), exactly as R20 ----
        // chunks 0-3 from LDS prefetch (identical bf16 bits), 4-15 streamed.
        {
            #pragma unroll
            for (int kk = 0; kk < 4; ++kk) {
                const int k0 = kk * 32 + kg * 8;
                s8v a = *(const s8v*)&xpre[(kk * 128 + tid) * 8];
                s8v br = *(const s8v*)&wih_lds[(0 * 16 + n) * WIH_LD + k0];
                s8v bz = *(const s8v*)&wih_lds[(1 * 16 + n) * WIH_LD + k0];
                s8v bn = *(const s8v*)&wih_lds[(2 * 16 + n) * WIH_LD + k0];
                acc_r  = __builtin_amdgcn_mfma_f32_16x16x32_bf16(a, br, acc_r,  0,0,0);
                acc_z  = __builtin_amdgcn_mfma_f32_16x16x32_bf16(a, bz, acc_z,  0,0,0);
                acc_in = __builtin_amdgcn_mfma_f32_16x16x32_bf16(a, bn, acc_in, 0,0,0);
            }
            const float* xrow = xlane + (size_t)t * IND;
            #pragma unroll 4
            for (int kk = 4; kk < IND / 32; ++kk) {
                const int k0 = kk * 32 + kg * 8;
                const float4* px = (const float4*)(xrow + kk * 32);
                float4 x0 = px[0], x1 = px[1];
                s8v a;
                a[0]=f2bf(x0.x); a[1]=f2bf(x0.y); a[2]=f2bf(x0.z); a[3]=f2bf(x0.w);
                a[4]=f2bf(x1.x); a[5]=f2bf(x1.y); a[6]=f2bf(x1.z); a[7]=f2bf(x1.w);
                s8v br = *(const s8v*)&wih_lds[(0 * 16 + n) * WIH_LD + k0];
                s8v bz = *(const s8v*)&wih_lds[(1 * 16 + n) * WIH_LD + k0];
                s8v bn = *(const s8v*)&wih_lds[(2 * 16 + n) * WIH_LD + k0];
                acc_r  = __builtin_amdgcn_mfma_f32_16x16x32_bf16(a, br, acc_r,  0,0,0);
                acc_z  = __builtin_amdgcn_mfma_f32_16x16x32_bf16(a, bz, acc_z,  0,0,0);
                acc_in = __builtin_amdgcn_mfma_f32_16x16x32_bf16(a, bn, acc_in, 0,0,0);
            }
        }

        // ---- gh: software-pipelined, 4 chunks of 8 kk (chunk 0 pre-loaded) ----
        if (t > 0) {
            __builtin_amdgcn_sched_barrier(0);
            #pragma unroll
            for (int c = 0; c < 4; ++c) {
                if (c < 3) {
                    #pragma unroll
                    for (int q = 0; q < 8; ++q) {             // issue chunk c+1
                        const int kk = (c + 1) * 8 + q;
                        u64 lo = __hip_atomic_load(hb + kk * 128,
                                                   __ATOMIC_RELAXED, __HIP_MEMORY_SCOPE_AGENT);
                        u64 hi = __hip_atomic_load(hb + kk * 128 + 1,
                                                   __ATOMIC_RELAXED, __HIP_MEMORY_SCOPE_AGENT);
                        union { u64 qq[2]; s8v v; } u; u.qq[0] = lo; u.qq[1] = hi;
                        areg[kk] = u.v;
                    }
                }
                __builtin_amdgcn_sched_barrier(0);
                #pragma unroll
                for (int q = 0; q < 8; ++q) {                 // consume chunk c
                    const int kk = c * 8 + q;
                    const int k0 = kk * 32 + kg * 8;
                    s8v br = *(const s8v*)&whh_lds[(0 * 16 + n) * WHH_LD + k0];
                    s8v bz = *(const s8v*)&whh_lds[(1 * 16 + n) * WHH_LD + k0];
                    s8v bn = *(const s8v*)&whh_lds[(2 * 16 + n) * WHH_LD + k0];
                    acc_r  = __builtin_amdgcn_mfma_f32_16x16x32_bf16(areg[kk], br, acc_r,  0,0,0);
                    acc_z  = __builtin_amdgcn_mfma_f32_16x16x32_bf16(areg[kk], bz, acc_z,  0,0,0);
                    acc_hn = __builtin_amdgcn_mfma_f32_16x16x32_bf16(areg[kk], bn, acc_hn, 0,0,0);
                }
                __builtin_amdgcn_sched_barrier(0);
            }
        }

        // ---- X[t+1] head loads: issue NOW (fly during epilogue) ----
        float4 xp[8];
        if (t < SS - 1) {
            const float* xrow = xlane + (size_t)(t + 1) * IND;
            #pragma unroll
            for (int c = 0; c < 4; ++c) {
                xp[2 * c]     = *(const float4*)(xrow + c * 32);
                xp[2 * c + 1] = *(const float4*)(xrow + c * 32 + 4);
            }
        }
        __builtin_amdgcn_sched_barrier(0);   // pin load issue before epilogue

        // ---- gates + state update (R16 epilogue; u64-packed h stores) ----
        u64 pack2[4];
        float hnew4[4];
        #pragma unroll
        for (int r = 0; r < 4; ++r) {
            float gr = acc_r[r] + bir + bhr;
            float gz = acc_z[r] + biz + bhz;
            float rr = 1.f / (1.f + __expf(-gr));
            float zz = 1.f / (1.f + __expf(-gz));
            float hn = acc_hn[r] + bhn;                       // t=0: == bhn
            float na = acc_in[r] + bin_ + rr * hn;
            float e2 = __expf(2.f * na);
            float nn = (e2 - 1.f) / (e2 + 1.f);
            float hnew = (1.f - zz) * nn + zz * hkeep[r];
            hkeep[r] = hnew;
            hnew4[r] = hnew;
            u32 hb16 = (u32)(unsigned short)f2bf(hnew);
            u32 p = hb16 | ((u32)__shfl_xor((int)hb16, 1) << 16); // cols n,n+1
            u32 q = (u32)__shfl_xor((int)p, 2);                   // cols n+2,n+3
            pack2[r] = (u64)p | ((u64)q << 32);                   // cols j..j+3
        }
        #pragma unroll
        for (int r = 0; r < 4; ++r) {
            const int b = rowbase + kg * 4 + r;
            out[(size_t)b * (SS * HID) + (size_t)t * HID + j] = hnew4[r];
            if (t == SS - 1)
                out[(size_t)BB * SS * HID + (size_t)b * HID + j] = hnew4[r];
        }

        if (t < SS - 1) {
            // ---- convert + park X[t+1] head in LDS (per-thread slices;
            // barrier's lgkmcnt drain orders these before next gi's reads)
            #pragma unroll
            for (int c = 0; c < 4; ++c) {
                float4 a0 = xp[2 * c], a1 = xp[2 * c + 1];
                s8v xv8;
                xv8[0]=f2bf(a0.x); xv8[1]=f2bf(a0.y); xv8[2]=f2bf(a0.z); xv8[3]=f2bf(a0.w);
                xv8[4]=f2bf(a1.x); xv8[5]=f2bf(a1.y); xv8[6]=f2bf(a1.z); xv8[7]=f2bf(a1.w);
                *(s8v*)&xpre[(c * 128 + tid) * 8] = xv8;
            }

            if (!(n & 3)) {
                char* base = (t & 1) ? ((char*)bufB + wbyteB) : ((char*)bufA + wbyteA);
                #pragma unroll
                for (int r = 0; r < 4; ++r)
                    __hip_atomic_store((u64*)(base + r * 16), pack2[r],
                                       __ATOMIC_RELAXED, __HIP_MEMORY_SCOPE_AGENT);
            }
            // ---- per-mi-group barrier (64 blocks), striped fan-in + poll.
            // __syncthreads drains vmcnt/lgkmcnt -> h stores at LLC, xpre
            // writes visible, before arrive. NOTHING between arrive and poll.
            __syncthreads();
            if (tid == 0) {
                __hip_atomic_fetch_add(&ctr[(mi * NSTRIPE + (blk & 7)) * 8], 1ull,
                                       __ATOMIC_RELAXED, __HIP_MEMORY_SCOPE_AGENT);
                const u64 target = (u64)GRPBLK * (u64)(t + 1);
                for (;;) {
                    u64 s = 0;
                    #pragma unroll
                    for (int i = 0; i < NSTRIPE; ++i)
                        s += __hip_atomic_load(&ctr[(mi * NSTRIPE + i) * 8],
                                               __ATOMIC_RELAXED,
                                               __HIP_MEMORY_SCOPE_AGENT);
                    if (s >= target) break;
                    __builtin_amdgcn_s_sleep(1);
                }
            }
            __syncthreads();
        }
    }
}

extern "C" void kernel_launch(void* const* d_in, const int* in_sizes, int n_in,
                              void* d_out, int out_size, void* d_ws, size_t ws_size,
                              hipStream_t stream) {
    const float* X   = (const float*)d_in[0];
    const float* Wih = (const float*)d_in[1];
    const float* Whh = (const float*)d_in[2];
    const float* bih = (const float*)d_in[3];
    const float* bhh = (const float*)d_in[4];
    float* out = (float*)d_out;

    u64*   ctr  = (u64*)d_ws;                         // 4x8 stripes on 64B stride
    short* bufA = (short*)((char*)d_ws + 4096);       // 256 KB (even-t h)
    // odd-t h: per-group 64 KB slices inside each group's OWN h_last rows
    // (tail bytes [mi*128KB, +64KB)); overwritten group-locally at t=SS-1
    // after the group's t=SS-2 barrier.
    short* bufB = (short*)(out + (size_t)BB * SS * HID);

    hipMemsetAsync(d_ws, 0, 4096, stream);            // zero barrier stripes

    void* args[] = { (void*)&X, (void*)&Wih, (void*)&Whh, (void*)&bih,
                     (void*)&bhh, (void*)&out, (void*)&bufA, (void*)&bufB,
                     (void*)&ctr };
    hipLaunchCooperativeKernel((const void*)gru_persistent,
                               dim3(NBLK), dim3(128), args, 0, stream);
}

// Round 24
// 3503.635 us; speedup vs baseline: 1.6109x; 1.6109x over previous
//
#include <hip/hip_runtime.h>
#include <hip/hip_bf16.h>

// Problem constants
#define BB   128
#define SS   512
#define IND  512
#define HID  1024
#define NBLK 256     // 4 row-quarters (mi) x 64 column-groups (jg)
#define GRPBLK 64    // blocks per mi-group (independent sub-GRU)
#define NSTRIPE 8    // stripes per group (one 64B LLC line each)

#define WHH_LD (HID + 8)   // LDS row pad
#define WIH_LD (IND + 8)

typedef __attribute__((ext_vector_type(8))) short s8v;   // 8 x bf16
typedef __attribute__((ext_vector_type(4))) float f4v;   // MFMA accumulator
typedef unsigned long long u64;
typedef unsigned int u32;

__device__ __forceinline__ short f2bf(float f) {
    union { float f; u32 u; } v; v.f = f;
    u32 u = v.u + 0x7FFFu + ((v.u >> 16) & 1u);          // RNE
    return (short)(u >> 16);
}

// FINAL = R20 (best verified: 3513us, absmax 0.00390625).
// h ping-pong layout (bf16):
//   bufA (ws): [wg=8][kk=32][kg=4][row 16][8 shorts]
//   bufB (out tail): group mi slice at mi*131072 + (wg&1)*32768 + rest
// Structure: persistent cooperative kernel, 256 blocks x 128 thr;
// LDS-resident bf16 weights; LLC-coherent (agent-scope relaxed atomic)
// h exchange; per-mi-group striped barrier; counted-vmcnt gh pipeline
// (4 chunks of 8 kk); u64-packed h stores; X[t+1]-head prefetch parked
// in LDS (transient regs -> no allocator spill; R19's register version
// spilled 8GB of scratch, R21/R22's load hoists regressed).

__global__ void __launch_bounds__(128, 1)
gru_persistent(const float* __restrict__ X,     // [B,S,IND]
               const float* __restrict__ Wih,   // [3H, IND]
               const float* __restrict__ Whh,   // [3H, HID]
               const float* __restrict__ bih,   // [3H]
               const float* __restrict__ bhh,   // [3H]
               float* __restrict__ out,         // [B,S,H] ++ [B,H]
               short* __restrict__ bufA,        // ws scratch (even t)
               short* __restrict__ bufB,        // d_out tail region (odd t)
               u64*   __restrict__ ctr)         // 4 groups x 8 stripes, 64B apart
{
    __shared__ __align__(16) short whh_lds[48 * WHH_LD];   // 99072 B
    __shared__ __align__(16) short wih_lds[48 * WIH_LD];   // 49920 B
    __shared__ __align__(16) short xpre[4 * 128 * 8];      //  8192 B [chunk][tid][8]

    const int tid  = threadIdx.x;
    const int wave = tid >> 6;      // 0..1
    const int lane = tid & 63;
    const int blk  = blockIdx.x;
    const int mi   = blk >> 6;      // 0..3 row quarter == barrier group
    const int jg   = blk & 63;      // column group

    // ---- stage weight slices to LDS as bf16 (once; R16/R8 layout) ----
    for (int idx = tid; idx < 48 * (HID / 4); idx += 128) {
        int s = idx / (HID / 4), k4 = idx % (HID / 4);
        int grow = (s >> 4) * HID + jg * 16 + (s & 15);
        float4 v = *(const float4*)(Whh + (size_t)grow * HID + k4 * 4);
        short* d = &whh_lds[s * WHH_LD + k4 * 4];
        d[0] = f2bf(v.x); d[1] = f2bf(v.y); d[2] = f2bf(v.z); d[3] = f2bf(v.w);
    }
    for (int idx = tid; idx < 48 * (IND / 4); idx += 128) {
        int s = idx / (IND / 4), k4 = idx % (IND / 4);
        int grow = (s >> 4) * HID + jg * 16 + (s & 15);
        float4 v = *(const float4*)(Wih + (size_t)grow * IND + k4 * 4);
        short* d = &wih_lds[s * WIH_LD + k4 * 4];
        d[0] = f2bf(v.x); d[1] = f2bf(v.y); d[2] = f2bf(v.z); d[3] = f2bf(v.w);
    }

    const int n  = lane & 15;
    const int kg = lane >> 4;
    const int j  = jg * 16 + n;
    const float bir = bih[j], biz = bih[HID + j], bin_ = bih[2 * HID + j];
    const float bhr = bhh[j], bhz = bhh[HID + j], bhn  = bhh[2 * HID + j];

    const int rowbase = mi * 32 + wave * 16;
    const int wg      = mi * 2 + wave;          // row-group = rowbase/16

    // writer byte offsets (lanes n%4==0 store packed u64 = cols j..j+3)
    const int wkk = j >> 5, wkg = (j >> 3) & 3;
    const u32 rest   = (u32)wkk * 1024u + (u32)wkg * 256u
                     + (u32)kg * 64u + ((u32)(n & 7) << 1);
    const u32 wbyteA = (u32)wg * 32768u + rest;
    const u32 wbyteB = (u32)mi * 131072u + (u32)(wg & 1) * 32768u + rest;

    // reader u64 offsets (lane-contiguous 16B per lane)
    const u64* hbA = (const u64*)bufA + (size_t)wg * 4096 + lane * 2;
    const u64* hbB = (const u64*)bufB + (size_t)mi * 16384
                   + (size_t)(wg & 1) * 4096 + lane * 2;

    const float* xlane = X + (size_t)(rowbase + n) * SS * IND + kg * 8;

    float hkeep[4] = {0.f, 0.f, 0.f, 0.f};      // this lane's own h elements

    // ---- prologue: fill xpre for t=0 (per-thread slices, no sync needed) ----
    {
        const float* xrow = xlane;
        #pragma unroll
        for (int c = 0; c < 4; ++c) {
            float4 a0 = *(const float4*)(xrow + c * 32);
            float4 a1 = *(const float4*)(xrow + c * 32 + 4);
            s8v xv8;
            xv8[0]=f2bf(a0.x); xv8[1]=f2bf(a0.y); xv8[2]=f2bf(a0.z); xv8[3]=f2bf(a0.w);
            xv8[4]=f2bf(a1.x); xv8[5]=f2bf(a1.y); xv8[6]=f2bf(a1.z); xv8[7]=f2bf(a1.w);
            *(s8v*)&xpre[(c * 128 + tid) * 8] = xv8;
        }
    }

    __syncthreads();

    for (int t = 0; t < SS; ++t) {
        f4v acc_r  = {0.f,0.f,0.f,0.f};
        f4v acc_z  = {0.f,0.f,0.f,0.f};
        f4v acc_in = {0.f,0.f,0.f,0.f};
        f4v acc_hn = {0.f,0.f,0.f,0.f};

        // ---- gi: X[:,t,:] @ Wih_slice^T (K=512) ----
        // chunks 0-3 from LDS prefetch (identical bf16 bits), 4-15 streamed.
        {
            #pragma unroll
            for (int kk = 0; kk < 4; ++kk) {
                const int k0 = kk * 32 + kg * 8;
                s8v a = *(const s8v*)&xpre[(kk * 128 + tid) * 8];
                s8v br = *(const s8v*)&wih_lds[(0 * 16 + n) * WIH_LD + k0];
                s8v bz = *(const s8v*)&wih_lds[(1 * 16 + n) * WIH_LD + k0];
                s8v bn = *(const s8v*)&wih_lds[(2 * 16 + n) * WIH_LD + k0];
                acc_r  = __builtin_amdgcn_mfma_f32_16x16x32_bf16(a, br, acc_r,  0,0,0);
                acc_z  = __builtin_amdgcn_mfma_f32_16x16x32_bf16(a, bz, acc_z,  0,0,0);
                acc_in = __builtin_amdgcn_mfma_f32_16x16x32_bf16(a, bn, acc_in, 0,0,0);
            }
            const float* xrow = xlane + (size_t)t * IND;
            #pragma unroll 4
            for (int kk = 4; kk < IND / 32; ++kk) {
                const int k0 = kk * 32 + kg * 8;
                const float4* px = (const float4*)(xrow + kk * 32);
                float4 x0 = px[0], x1 = px[1];
                s8v a;
                a[0]=f2bf(x0.x); a[1]=f2bf(x0.y); a[2]=f2bf(x0.z); a[3]=f2bf(x0.w);
                a[4]=f2bf(x1.x); a[5]=f2bf(x1.y); a[6]=f2bf(x1.z); a[7]=f2bf(x1.w);
                s8v br = *(const s8v*)&wih_lds[(0 * 16 + n) * WIH_LD + k0];
                s8v bz = *(const s8v*)&wih_lds[(1 * 16 + n) * WIH_LD + k0];
                s8v bn = *(const s8v*)&wih_lds[(2 * 16 + n) * WIH_LD + k0];
                acc_r  = __builtin_amdgcn_mfma_f32_16x16x32_bf16(a, br, acc_r,  0,0,0);
                acc_z  = __builtin_amdgcn_mfma_f32_16x16x32_bf16(a, bz, acc_z,  0,0,0);
                acc_in = __builtin_amdgcn_mfma_f32_16x16x32_bf16(a, bn, acc_in, 0,0,0);
            }
        }

        // ---- gh: software-pipelined, 4 chunks of 8 kk (R16 structure) ----
        if (t > 0) {
            const u64* hb = (t & 1) ? hbA : hbB;              // h_{t-1}
            s8v areg[32];
            #pragma unroll
            for (int q = 0; q < 8; ++q) {                     // chunk 0
                u64 lo = __hip_atomic_load(hb + q * 128,
                                           __ATOMIC_RELAXED, __HIP_MEMORY_SCOPE_AGENT);
                u64 hi = __hip_atomic_load(hb + q * 128 + 1,
                                           __ATOMIC_RELAXED, __HIP_MEMORY_SCOPE_AGENT);
                union { u64 qq[2]; s8v v; } u; u.qq[0] = lo; u.qq[1] = hi;
                areg[q] = u.v;
            }
            __builtin_amdgcn_sched_barrier(0);
            #pragma unroll
            for (int c = 0; c < 4; ++c) {
                if (c < 3) {
                    #pragma unroll
                    for (int q = 0; q < 8; ++q) {             // issue chunk c+1
                        const int kk = (c + 1) * 8 + q;
                        u64 lo = __hip_atomic_load(hb + kk * 128,
                                                   __ATOMIC_RELAXED, __HIP_MEMORY_SCOPE_AGENT);
                        u64 hi = __hip_atomic_load(hb + kk * 128 + 1,
                                                   __ATOMIC_RELAXED, __HIP_MEMORY_SCOPE_AGENT);
                        union { u64 qq[2]; s8v v; } u; u.qq[0] = lo; u.qq[1] = hi;
                        areg[kk] = u.v;
                    }
                }
                __builtin_amdgcn_sched_barrier(0);
                #pragma unroll
                for (int q = 0; q < 8; ++q) {                 // consume chunk c
                    const int kk = c * 8 + q;
                    const int k0 = kk * 32 + kg * 8;
                    s8v br = *(const s8v*)&whh_lds[(0 * 16 + n) * WHH_LD + k0];
                    s8v bz = *(const s8v*)&whh_lds[(1 * 16 + n) * WHH_LD + k0];
                    s8v bn = *(const s8v*)&whh_lds[(2 * 16 + n) * WHH_LD + k0];
                    acc_r  = __builtin_amdgcn_mfma_f32_16x16x32_bf16(areg[kk], br, acc_r,  0,0,0);
                    acc_z  = __builtin_amdgcn_mfma_f32_16x16x32_bf16(areg[kk], bz, acc_z,  0,0,0);
                    acc_hn = __builtin_amdgcn_mfma_f32_16x16x32_bf16(areg[kk], bn, acc_hn, 0,0,0);
                }
                __builtin_amdgcn_sched_barrier(0);
            }
        }

        // ---- X[t+1] head loads: issue NOW (fly during epilogue) ----
        float4 xp[8];
        if (t < SS - 1) {
            const float* xrow = xlane + (size_t)(t + 1) * IND;
            #pragma unroll
            for (int c = 0; c < 4; ++c) {
                xp[2 * c]     = *(const float4*)(xrow + c * 32);
                xp[2 * c + 1] = *(const float4*)(xrow + c * 32 + 4);
            }
        }
        __builtin_amdgcn_sched_barrier(0);   // pin load issue before epilogue

        // ---- gates + state update (R16 epilogue; u64-packed h stores) ----
        u64 pack2[4];
        float hnew4[4];
        #pragma unroll
        for (int r = 0; r < 4; ++r) {
            float gr = acc_r[r] + bir + bhr;
            float gz = acc_z[r] + biz + bhz;
            float rr = 1.f / (1.f + __expf(-gr));
            float zz = 1.f / (1.f + __expf(-gz));
            float hn = acc_hn[r] + bhn;                       // t=0: == bhn
            float na = acc_in[r] + bin_ + rr * hn;
            float e2 = __expf(2.f * na);
            float nn = (e2 - 1.f) / (e2 + 1.f);
            float hnew = (1.f - zz) * nn + zz * hkeep[r];
            hkeep[r] = hnew;
            hnew4[r] = hnew;
            u32 hb16 = (u32)(unsigned short)f2bf(hnew);
            u32 p = hb16 | ((u32)__shfl_xor((int)hb16, 1) << 16); // cols n,n+1
            u32 q = (u32)__shfl_xor((int)p, 2);                   // cols n+2,n+3
            pack2[r] = (u64)p | ((u64)q << 32);                   // cols j..j+3
        }
        #pragma unroll
        for (int r = 0; r < 4; ++r) {
            const int b = rowbase + kg * 4 + r;
            out[(size_t)b * (SS * HID) + (size_t)t * HID + j] = hnew4[r];
            if (t == SS - 1)
                out[(size_t)BB * SS * HID + (size_t)b * HID + j] = hnew4[r];
        }

        if (t < SS - 1) {
            // ---- convert + park X[t+1] head in LDS (per-thread slices;
            // barrier's lgkmcnt drain orders these before next gi's reads)
            #pragma unroll
            for (int c = 0; c < 4; ++c) {
                float4 a0 = xp[2 * c], a1 = xp[2 * c + 1];
                s8v xv8;
                xv8[0]=f2bf(a0.x); xv8[1]=f2bf(a0.y); xv8[2]=f2bf(a0.z); xv8[3]=f2bf(a0.w);
                xv8[4]=f2bf(a1.x); xv8[5]=f2bf(a1.y); xv8[6]=f2bf(a1.z); xv8[7]=f2bf(a1.w);
                *(s8v*)&xpre[(c * 128 + tid) * 8] = xv8;
            }

            if (!(n & 3)) {
                char* base = (t & 1) ? ((char*)bufB + wbyteB) : ((char*)bufA + wbyteA);
                #pragma unroll
                for (int r = 0; r < 4; ++r)
                    __hip_atomic_store((u64*)(base + r * 16), pack2[r],
                                       __ATOMIC_RELAXED, __HIP_MEMORY_SCOPE_AGENT);
            }
            // ---- per-mi-group barrier (64 blocks), striped fan-in + poll.
            // __syncthreads drains vmcnt/lgkmcnt -> h stores at LLC, xpre
            // writes visible, before arrive. NOTHING between arrive and poll.
            __syncthreads();
            if (tid == 0) {
                __hip_atomic_fetch_add(&ctr[(mi * NSTRIPE + (blk & 7)) * 8], 1ull,
                                       __ATOMIC_RELAXED, __HIP_MEMORY_SCOPE_AGENT);
                const u64 target = (u64)GRPBLK * (u64)(t + 1);
                for (;;) {
                    u64 s = 0;
                    #pragma unroll
                    for (int i = 0; i < NSTRIPE; ++i)
                        s += __hip_atomic_load(&ctr[(mi * NSTRIPE + i) * 8],
                                               __ATOMIC_RELAXED,
                                               __HIP_MEMORY_SCOPE_AGENT);
                    if (s >= target) break;
                    __builtin_amdgcn_s_sleep(1);
                }
            }
            __syncthreads();
        }
    }
}

extern "C" void kernel_launch(void* const* d_in, const int* in_sizes, int n_in,
                              void* d_out, int out_size, void* d_ws, size_t ws_size,
                              hipStream_t stream) {
    const float* X   = (const float*)d_in[0];
    const float* Wih = (const float*)d_in[1];
    const float* Whh = (const float*)d_in[2];
    const float* bih = (const float*)d_in[3];
    const float* bhh = (const float*)d_in[4];
    float* out = (float*)d_out;

    u64*   ctr  = (u64*)d_ws;                         // 4x8 stripes on 64B stride
    short* bufA = (short*)((char*)d_ws + 4096);       // 256 KB (even-t h)
    // odd-t h: per-group 64 KB slices inside each group's OWN h_last rows
    // (tail bytes [mi*128KB, +64KB)); overwritten group-locally at t=SS-1
    // after the group's t=SS-2 barrier.
    short* bufB = (short*)(out + (size_t)BB * SS * HID);

    hipMemsetAsync(d_ws, 0, 4096, stream);            // zero barrier stripes

    void* args[] = { (void*)&X, (void*)&Wih, (void*)&Whh, (void*)&bih,
                     (void*)&bhh, (void*)&out, (void*)&bufA, (void*)&bufB,
                     (void*)&ctr };
    hipLaunchCooperativeKernel((const void*)gru_persistent,
                               dim3(NBLK), dim3(128), args, 0, stream);
}